// Round 6
// baseline (665.009 us; speedup 1.0000x reference)
//
#include <hip/hip_runtime.h>
#include <math.h>

// ---------------------------------------------------------------------------
// R6: CSR deleted. Aggregation is edge-parallel per 128-node bucket:
//     one block per bucket, LDS fp32 accumulators (stride 9, conflict-free),
//     gather t[src] (16B) + ds_add_f32 per feature. Threads pull uint4 groups
//     off a flattened (run-scan + map) index space -> zero degree divergence.
//     bin_sort: CHUNK 4096 (782 blocks), runs padded to 4-aligned with
//     bit31 sentinels so agg readers use pure uint4 loads.
//     Kernels: bin_sort(+transform1), agg1, gcn2_fused, agg3_mlp.  No memsets.
// ---------------------------------------------------------------------------

#define CHUNK 4096       // edges per bin_sort block
#define PSTR  6464       // padded block region: 4096 + 782*3 pad slack (<=6442)
#define BW    128        // nodes per bucket (dst >> 7)
#define MAXNB 800        // >= NB = 782 buckets
#define MAXG  2048       // >= max uint4 groups per bucket (~1675 worst)

typedef _Float16 half8 __attribute__((ext_vector_type(8)));

static __device__ __forceinline__ float sigmoidf_(float x) {
    return 1.0f / (1.0f + expf(-x));
}

// exclusive 256-scan; s[255] holds the inclusive total afterwards
static __device__ __forceinline__ int scan256_excl(int v, int* s) {
    int tid = threadIdx.x;
    s[tid] = v;
    for (int off = 1; off < 256; off <<= 1) {
        __syncthreads();
        int t = (tid >= off) ? s[tid - off] : 0;
        __syncthreads();
        s[tid] += t;
    }
    __syncthreads();
    return s[tid] - v;
}

// ---- bin_sort + layer-1 transform ----------------------------------------
__global__ __launch_bounds__(256)
void bin_sort_kernel(const float* __restrict__ x, const float* __restrict__ W1r,
                     const float* __restrict__ b1v, const float* __restrict__ W1o,
                     _Float16* __restrict__ t1, _Float16* __restrict__ z1,
                     const int* __restrict__ src, const int* __restrict__ dst,
                     unsigned* __restrict__ packed, int* __restrict__ counts_bm,
                     int* __restrict__ lstart_bm,
                     int E, int N, int NB, int NBLK) {
    __shared__ int s_hist[MAXNB];
    __shared__ int s_cur[MAXNB];
    __shared__ unsigned s_pk[PSTR];
    __shared__ int s_scan[256];
    __shared__ float sW[264];          // Wr1(128) Wo1(128) b1(8)
    int tid = threadIdx.x, blk = blockIdx.x;

    if (tid < 128) { sW[tid] = W1r[tid]; sW[128 + tid] = W1o[tid]; }
    if (tid < 8) sW[256 + tid] = b1v[tid];
    for (int i = tid; i < NB; i += 256) s_hist[i] = 0;
    __syncthreads();

    // phase 0: t1 = x@Wr1, z1 = x@Wo1 + b1 (independent of sort)
    {
        int node = blk * 256 + tid;
        if (node < N) {
            const float4* x4 = (const float4*)x;
            float xv[16];
#pragma unroll
            for (int k = 0; k < 4; ++k) {
                float4 v = x4[node * 4 + k];
                xv[4 * k] = v.x; xv[4 * k + 1] = v.y;
                xv[4 * k + 2] = v.z; xv[4 * k + 3] = v.w;
            }
            float ta[8], za[8];
#pragma unroll
            for (int j = 0; j < 8; ++j) { ta[j] = 0.0f; za[j] = sW[256 + j]; }
#pragma unroll
            for (int f = 0; f < 16; ++f) {
                float xf = xv[f];
#pragma unroll
                for (int j = 0; j < 8; ++j) {
                    ta[j] += xf * sW[f * 8 + j];
                    za[j] += xf * sW[128 + f * 8 + j];
                }
            }
            half8 th, zh;
#pragma unroll
            for (int j = 0; j < 8; ++j) { th[j] = (_Float16)ta[j]; zh[j] = (_Float16)za[j]; }
            ((half8*)t1)[node] = th;
            ((half8*)z1)[node] = zh;
        }
    }
    if (blk >= NBLK) return;

    int base = blk * CHUNK;
    int cnt = E - base; if (cnt > CHUNK) cnt = CHUNK;

    // phase 1: histogram of dst buckets
    if (cnt == CHUNK) {
        const int4* d4 = (const int4*)(dst + base);
#pragma unroll
        for (int k = 0; k < CHUNK / 1024; ++k) {
            int4 d = d4[k * 256 + tid];
            atomicAdd(&s_hist[d.x >> 7], 1);
            atomicAdd(&s_hist[d.y >> 7], 1);
            atomicAdd(&s_hist[d.z >> 7], 1);
            atomicAdd(&s_hist[d.w >> 7], 1);
        }
    } else {
        for (int i = tid; i < cnt; i += 256) atomicAdd(&s_hist[dst[base + i] >> 7], 1);
    }
    __syncthreads();

    // phase 2: exclusive scan of 4-aligned run sizes -> padded run starts
    int per = (NB + 255) / 256;
    int st = tid * per;
    int lsum = 0;
    for (int j = 0; j < per; ++j)
        if (st + j < NB) lsum += (s_hist[st + j] + 3) & ~3;
    int excl = scan256_excl(lsum, s_scan);
    int padtot = s_scan[255];
    int run = excl;
    for (int j = 0; j < per; ++j)
        if (st + j < NB) { s_cur[st + j] = run; run += (s_hist[st + j] + 3) & ~3; }
    __syncthreads();

    // phase 3a: sentinel prefill of the padded region
    for (int i = tid; i < padtot; i += 256) s_pk[i] = 0x80000000u;
    __syncthreads();

    // phase 3b: re-read (L2-hot) and scatter into LDS, bucket-grouped
    if (cnt == CHUNK) {
        const int4* d4 = (const int4*)(dst + base);
        const int4* s4 = (const int4*)(src + base);
#pragma unroll
        for (int k = 0; k < CHUNK / 1024; ++k) {
            int4 d = d4[k * 256 + tid];
            int4 s = s4[k * 256 + tid];
            int dd[4] = {d.x, d.y, d.z, d.w};
            int ss[4] = {s.x, s.y, s.z, s.w};
#pragma unroll
            for (int j = 0; j < 4; ++j) {
                int pos = atomicAdd(&s_cur[dd[j] >> 7], 1);
                s_pk[pos] = ((unsigned)(dd[j] & 127) << 17) | (unsigned)ss[j];
            }
        }
    } else {
        for (int i = tid; i < cnt; i += 256) {
            int d = dst[base + i], s = src[base + i];
            int pos = atomicAdd(&s_cur[d >> 7], 1);
            s_pk[pos] = ((unsigned)(d & 127) << 17) | (unsigned)s;
        }
    }
    __syncthreads();

    // phase 4: block-major write + per-(blk,bucket) tables
    for (int i = tid; i < padtot; i += 256) packed[(size_t)blk * PSTR + i] = s_pk[i];
    for (int i = tid; i < NB; i += 256) {
        int h = s_hist[i];
        counts_bm[blk * NB + i] = h;
        lstart_bm[blk * NB + i] = s_cur[i] - h;   // = padded run start
    }
}

// ---- shared bucket accumulator -------------------------------------------
struct AggLds {
    float acc[BW * 9];                 // stride 9: bank-conflict-free
    int s_cnt[MAXNB], s_lst[MAXNB], s_goff[MAXNB];
    int s_map[MAXG];
    int s_scan[256];
};

template <bool COUNT>
static __device__ __forceinline__ void bucket_accumulate(
    const half8* __restrict__ t, const unsigned* __restrict__ packed,
    const int* __restrict__ counts_bm, const int* __restrict__ lstart_bm,
    int b, int NB, int NBLK, AggLds& L, int* dcnt) {
    int tid = threadIdx.x;
    for (int i = tid; i < BW * 9; i += 256) L.acc[i] = 0.0f;
    for (int i = tid; i < NBLK; i += 256) {
        L.s_cnt[i] = counts_bm[i * NB + b];
        L.s_lst[i] = lstart_bm[i * NB + b];
    }
    __syncthreads();

    // scan of per-run uint4-group counts -> flat group space
    int per = (NBLK + 255) / 256;
    int st = tid * per;
    int lsum = 0;
    for (int j = 0; j < per; ++j)
        if (st + j < NBLK) lsum += (L.s_cnt[st + j] + 3) >> 2;
    int excl = scan256_excl(lsum, L.s_scan);
    int G = L.s_scan[255];
    int run = excl;
    for (int j = 0; j < per; ++j)
        if (st + j < NBLK) { L.s_goff[st + j] = run; run += (L.s_cnt[st + j] + 3) >> 2; }
    __syncthreads();
    if (G > MAXG) G = MAXG;

    // group -> run map (perfect balance for the processing loop)
    for (int i = tid; i < NBLK; i += 256) {
        int g0 = L.s_goff[i], gc = (L.s_cnt[i] + 3) >> 2;
        int ge = g0 + gc; if (ge > MAXG) ge = MAXG;
        for (int g = g0; g < ge; ++g) L.s_map[g] = i;
    }
    __syncthreads();

    // edge-parallel gather + LDS fp32 accumulate
    for (int g = tid; g < G; g += 256) {
        int r = L.s_map[g];
        int j = (g - L.s_goff[r]) << 2;
        uint4 v = *(const uint4*)(packed + (size_t)r * PSTR + L.s_lst[r] + j);
        unsigned w[4] = {v.x, v.y, v.z, v.w};
        half8 f[4];
#pragma unroll
        for (int k = 0; k < 4; ++k) f[k] = t[w[k] & 0x1FFFF];   // sentinel -> t[0], dead
#pragma unroll
        for (int k = 0; k < 4; ++k) {
            if (!(w[k] >> 31)) {
                int dl = (w[k] >> 17) & 127;
#pragma unroll
                for (int c = 0; c < 8; ++c)
                    atomicAdd(&L.acc[dl * 9 + c], (float)f[k][c]);
                if (COUNT) atomicAdd(&dcnt[dl], 1);
            }
        }
    }
    __syncthreads();
}

// ---- layer 1: h1 = sigmoid(mean(t1) + z1); also emits invd ----------------
__global__ __launch_bounds__(256)
void agg1_kernel(const _Float16* __restrict__ t1, const _Float16* __restrict__ z1,
                 const unsigned* __restrict__ packed,
                 const int* __restrict__ counts_bm, const int* __restrict__ lstart_bm,
                 float* __restrict__ invd, _Float16* __restrict__ h1,
                 int N, int NB, int NBLK) {
    __shared__ AggLds L;
    __shared__ int dcnt[BW];
    int tid = threadIdx.x, b = blockIdx.x;
    for (int i = tid; i < BW; i += 256) dcnt[i] = 0;
    bucket_accumulate<true>((const half8*)t1, packed, counts_bm, lstart_bm, b, NB, NBLK, L, dcnt);
    if (tid < BW) {
        int node = b * BW + tid;
        if (node < N) {
            int d = dcnt[tid];
            float inv = 1.0f / (float)(d > 0 ? d : 1);
            invd[node] = inv;
            half8 z = ((const half8*)z1)[node];
            half8 o;
#pragma unroll
            for (int c = 0; c < 8; ++c)
                o[c] = (_Float16)sigmoidf_(L.acc[tid * 9 + c] * inv + (float)z[c]);
            ((half8*)h1)[node] = o;
        }
    }
}

// ---- layer 2 + layer-3 transform -----------------------------------------
__global__ __launch_bounds__(256)
void gcn2_fused_kernel(const _Float16* __restrict__ h1, const float* __restrict__ invd,
                       const unsigned* __restrict__ packed,
                       const int* __restrict__ counts_bm, const int* __restrict__ lstart_bm,
                       const float* __restrict__ W2r, const float* __restrict__ b2,
                       const float* __restrict__ W2o,
                       const float* __restrict__ W3r, const float* __restrict__ b3,
                       const float* __restrict__ W3o,
                       _Float16* __restrict__ t3, _Float16* __restrict__ z3,
                       int N, int NB, int NBLK) {
    __shared__ AggLds L;
    __shared__ float sW2r[128], sW2o[128], sW3r[128], sW3o[128], sb2[16], sb3[8];
    int tid = threadIdx.x, b = blockIdx.x;
    if (tid < 128) {
        sW2r[tid] = W2r[tid]; sW2o[tid] = W2o[tid];
        sW3r[tid] = W3r[tid]; sW3o[tid] = W3o[tid];
    }
    if (tid < 16) sb2[tid] = b2[tid];
    if (tid < 8) sb3[tid] = b3[tid];
    bucket_accumulate<false>((const half8*)h1, packed, counts_bm, lstart_bm, b, NB, NBLK, L, nullptr);
    if (tid < BW) {
        int node = b * BW + tid;
        if (node < N) {
            float inv = invd[node];
            half8 sf = ((const half8*)h1)[node];
            float m[8], x8[8];
#pragma unroll
            for (int c = 0; c < 8; ++c) {
                m[c] = L.acc[tid * 9 + c] * inv;
                x8[c] = (float)sf[c];
            }
            float v16[16];
#pragma unroll
            for (int j = 0; j < 16; ++j) {
                float a = sb2[j];
#pragma unroll
                for (int f = 0; f < 8; ++f)
                    a += m[f] * sW2r[f * 16 + j] + x8[f] * sW2o[f * 16 + j];
                v16[j] = sigmoidf_(a);
            }
            float ta[8], za[8];
#pragma unroll
            for (int j = 0; j < 8; ++j) { ta[j] = 0.0f; za[j] = sb3[j]; }
#pragma unroll
            for (int f = 0; f < 16; ++f) {
                float hv = v16[f];
#pragma unroll
                for (int j = 0; j < 8; ++j) {
                    ta[j] += hv * sW3r[f * 8 + j];
                    za[j] += hv * sW3o[f * 8 + j];
                }
            }
            half8 th, zh;
#pragma unroll
            for (int j = 0; j < 8; ++j) { th[j] = (_Float16)ta[j]; zh[j] = (_Float16)za[j]; }
            ((half8*)t3)[node] = th;
            ((half8*)z3)[node] = zh;
        }
    }
}

// ---- layer 3 + full MLP head ---------------------------------------------
__global__ __launch_bounds__(256)
void agg3_mlp_kernel(const _Float16* __restrict__ t3, const _Float16* __restrict__ z3,
                     const float* __restrict__ invd,
                     const unsigned* __restrict__ packed,
                     const int* __restrict__ counts_bm, const int* __restrict__ lstart_bm,
                     const float* __restrict__ fc1W, const float* __restrict__ fc1b,
                     const float* __restrict__ fc2W, const float* __restrict__ fc2b,
                     float* __restrict__ out, int N, int NB, int NBLK) {
    __shared__ AggLds L;
    __shared__ float sW1[256], sb1[32], sW2[32];
    __shared__ float sb2_;
    int tid = threadIdx.x, b = blockIdx.x;
    if (tid < 256) sW1[tid] = fc1W[tid];
    if (tid < 32) { sb1[tid] = fc1b[tid]; sW2[tid] = fc2W[tid]; }
    if (tid == 0) sb2_ = fc2b[0];
    bucket_accumulate<false>((const half8*)t3, packed, counts_bm, lstart_bm, b, NB, NBLK, L, nullptr);
    if (tid < BW) {
        int node = b * BW + tid;
        if (node < N) {
            float inv = invd[node];
            half8 z = ((const half8*)z3)[node];
            float h[8];
#pragma unroll
            for (int c = 0; c < 8; ++c)
                h[c] = sigmoidf_(L.acc[tid * 9 + c] * inv + (float)z[c]);
            float acc = sb2_;
#pragma unroll
            for (int j = 0; j < 32; ++j) {
                float a = sb1[j];
#pragma unroll
                for (int f = 0; f < 8; ++f) a += h[f] * sW1[f * 32 + j];
                acc += sW2[j] * sigmoidf_(a);
            }
            out[node] = acc;
        }
    }
}

extern "C" void kernel_launch(void* const* d_in, const int* in_sizes, int n_in,
                              void* d_out, int out_size, void* d_ws, size_t ws_size,
                              hipStream_t stream) {
    const float* x      = (const float*)d_in[0];
    const int*   ei     = (const int*)d_in[1];
    const float* Wrel1  = (const float*)d_in[2];
    const float* b1     = (const float*)d_in[3];
    const float* Wroot1 = (const float*)d_in[4];
    const float* Wrel2  = (const float*)d_in[5];
    const float* b2     = (const float*)d_in[6];
    const float* Wroot2 = (const float*)d_in[7];
    const float* Wrel3  = (const float*)d_in[8];
    const float* b3     = (const float*)d_in[9];
    const float* Wroot3 = (const float*)d_in[10];
    const float* fc1W   = (const float*)d_in[11];
    const float* fc1b   = (const float*)d_in[12];
    const float* fc2W   = (const float*)d_in[13];
    const float* fc2b   = (const float*)d_in[14];
    float* out = (float*)d_out;

    const int N = in_sizes[0] / 16;
    const int E = in_sizes[1] / 2;
    const int* e_src = ei;
    const int* e_dst = ei + E;

    const int NB   = (N + BW - 1) / BW;           // 782
    const int NBLK = (E + CHUNK - 1) / CHUNK;     // 782
    const int nbN  = (N + 255) / 256;             // 391

    char* ws = (char*)d_ws;
    size_t off = 0;
    auto alloc = [&](size_t bytes) { char* p = ws + off; off += (bytes + 15) & ~size_t(15); return p; };
    unsigned* packed   = (unsigned*)alloc((size_t)NBLK * PSTR * 4);
    int* counts_bm     = (int*)alloc((size_t)NBLK * NB * 4);
    int* lstart_bm     = (int*)alloc((size_t)NBLK * NB * 4);
    float* invd        = (float*)alloc((size_t)N * 4);
    _Float16* t1       = (_Float16*)alloc((size_t)N * 8 * 2);
    _Float16* z1       = (_Float16*)alloc((size_t)N * 8 * 2);
    _Float16* h1       = (_Float16*)alloc((size_t)N * 8 * 2);
    _Float16* t3       = (_Float16*)alloc((size_t)N * 8 * 2);
    _Float16* z3       = (_Float16*)alloc((size_t)N * 8 * 2);

    const int gbuild = (NBLK > nbN) ? NBLK : nbN;   // 782 covers transform too
    bin_sort_kernel<<<gbuild, 256, 0, stream>>>(
        x, Wrel1, b1, Wroot1, t1, z1, e_src, e_dst,
        packed, counts_bm, lstart_bm, E, N, NB, NBLK);
    agg1_kernel<<<NB, 256, 0, stream>>>(t1, z1, packed, counts_bm, lstart_bm,
                                        invd, h1, N, NB, NBLK);
    gcn2_fused_kernel<<<NB, 256, 0, stream>>>(h1, invd, packed, counts_bm, lstart_bm,
                                              Wrel2, b2, Wroot2, Wrel3, b3, Wroot3,
                                              t3, z3, N, NB, NBLK);
    agg3_mlp_kernel<<<NB, 256, 0, stream>>>(t3, z3, invd, packed, counts_bm, lstart_bm,
                                            fc1W, fc1b, fc2W, fc2b, out, N, NB, NBLK);
}

// Round 7
// 248.316 us; speedup vs baseline: 2.6781x; 2.6781x over previous
//
#include <hip/hip_runtime.h>
#include <math.h>

// ---------------------------------------------------------------------------
// R7 = R5 structure (bin_sort+transform1 -> bucket_sort -> agg1 -> gcn2_fused
//      -> agg3_mlp; linear csr streams) + 4-way node-split aggregation:
//      4 lanes per node, each takes every 4th int4 csr chunk, partials
//      combined via quad-local __shfl_xor -> 4x waves & outstanding gathers.
//      (R6's edge-parallel LDS-atomic design regressed 3x: pointer-chasing
//      scattered runs + dependent LDS atomics at 3 blocks/CU. Reverted.)
// ---------------------------------------------------------------------------

#define CHUNK  8192        // edges per bin_sort block
#define PSTR   10752       // padded region stride: CHUNK + 4-align pad slack
#define BW     128         // nodes per bucket (dst >> 7)
#define MAXB   6144        // max padded edges per bucket
#define MAXNB  800         // >= NB = 782
#define MAXBLK 512         // >= NBLK = 391

typedef _Float16 half8 __attribute__((ext_vector_type(8)));

static __device__ __forceinline__ float sigmoidf_(float x) {
    return 1.0f / (1.0f + expf(-x));
}

// exclusive 256-scan; s[255] holds the inclusive total afterwards
static __device__ __forceinline__ int scan256_excl(int v, int* s) {
    int tid = threadIdx.x;
    s[tid] = v;
    for (int off = 1; off < 256; off <<= 1) {
        __syncthreads();
        int t = (tid >= off) ? s[tid - off] : 0;
        __syncthreads();
        s[tid] += t;
    }
    __syncthreads();
    return s[tid] - v;
}

// quarter-gather: lane-quarter q of a node processes int4 chunks q, q+4, ...
// full chunks are branch-free (4 independent gathers); tail chunk masked.
static __device__ __forceinline__ void gather_quarter8(
    const half8* __restrict__ t, const int* __restrict__ csr,
    int rs, int d, int q, float* s) {
#pragma unroll
    for (int c = 0; c < 8; ++c) s[c] = 0.0f;
    int nf = d >> 2;                      // full int4 chunks
    for (int c4 = q; c4 < nf; c4 += 4) {
        int4 ci = *(const int4*)(csr + rs + (c4 << 2));
        half8 v0 = t[ci.x]; half8 v1 = t[ci.y];
        half8 v2 = t[ci.z]; half8 v3 = t[ci.w];
#pragma unroll
        for (int c = 0; c < 8; ++c)
            s[c] += ((float)v0[c] + (float)v1[c]) + ((float)v2[c] + (float)v3[c]);
    }
    int tailc = d & 3;
    if (tailc && ((nf & 3) == q)) {       // this quarter owns the tail chunk
        int e0 = nf << 2;
        int4 ci = *(const int4*)(csr + rs + e0);   // row padded to 4-aligned
        half8 v0 = t[ci.x];
#pragma unroll
        for (int c = 0; c < 8; ++c) s[c] += (float)v0[c];
        if (tailc > 1) {
            half8 v = t[ci.y];
#pragma unroll
            for (int c = 0; c < 8; ++c) s[c] += (float)v[c];
        }
        if (tailc > 2) {
            half8 v = t[ci.z];
#pragma unroll
            for (int c = 0; c < 8; ++c) s[c] += (float)v[c];
        }
    }
}

// combine quad partials (lanes xor 1, xor 2) -> full sum on all 4 lanes
static __device__ __forceinline__ void quad_reduce8(float* s) {
#pragma unroll
    for (int c = 0; c < 8; ++c) s[c] += __shfl_xor(s[c], 1, 64);
#pragma unroll
    for (int c = 0; c < 8; ++c) s[c] += __shfl_xor(s[c], 2, 64);
}

// ---- bin_sort + transform1 -----------------------------------------------
__global__ __launch_bounds__(256)
void bin_sort_kernel(const float* __restrict__ x, const float* __restrict__ W1r,
                     const float* __restrict__ b1v, const float* __restrict__ W1o,
                     _Float16* __restrict__ t1, _Float16* __restrict__ z1,
                     const int* __restrict__ src, const int* __restrict__ dst,
                     unsigned* __restrict__ packed, int* __restrict__ counts_bm,
                     int* __restrict__ lstart_bm, int* __restrict__ btot,
                     int E, int N, int NB, int NBLK) {
    __shared__ int s_hist[MAXNB];
    __shared__ int s_cur[MAXNB];
    __shared__ unsigned s_pk[PSTR];
    __shared__ int s_scan[256];
    __shared__ float sW[264];          // Wr1(128) Wo1(128) b1(8)
    int tid = threadIdx.x, blk = blockIdx.x;

    if (tid < 128) { sW[tid] = W1r[tid]; sW[128 + tid] = W1o[tid]; }
    if (tid < 8) sW[256 + tid] = b1v[tid];
    for (int i = tid; i < NB; i += 256) s_hist[i] = 0;
    __syncthreads();

    // phase 0: t1 = x@Wr1, z1 = x@Wo1 + b1
    {
        int node = blk * 256 + tid;
        if (node < N) {
            const float4* x4 = (const float4*)x;
            float xv[16];
#pragma unroll
            for (int k = 0; k < 4; ++k) {
                float4 v = x4[node * 4 + k];
                xv[4 * k] = v.x; xv[4 * k + 1] = v.y;
                xv[4 * k + 2] = v.z; xv[4 * k + 3] = v.w;
            }
            float ta[8], za[8];
#pragma unroll
            for (int j = 0; j < 8; ++j) { ta[j] = 0.0f; za[j] = sW[256 + j]; }
#pragma unroll
            for (int f = 0; f < 16; ++f) {
                float xf = xv[f];
#pragma unroll
                for (int j = 0; j < 8; ++j) {
                    ta[j] += xf * sW[f * 8 + j];
                    za[j] += xf * sW[128 + f * 8 + j];
                }
            }
            half8 th, zh;
#pragma unroll
            for (int j = 0; j < 8; ++j) { th[j] = (_Float16)ta[j]; zh[j] = (_Float16)za[j]; }
            ((half8*)t1)[node] = th;
            ((half8*)z1)[node] = zh;
        }
    }
    if (blk >= NBLK) return;

    int base = blk * CHUNK;
    int cnt = E - base; if (cnt > CHUNK) cnt = CHUNK;

    // phase 1: histogram of dst buckets
    if (cnt == CHUNK) {
        const int4* d4 = (const int4*)(dst + base);
#pragma unroll
        for (int k = 0; k < CHUNK / 1024; ++k) {
            int4 d = d4[k * 256 + tid];
            atomicAdd(&s_hist[d.x >> 7], 1);
            atomicAdd(&s_hist[d.y >> 7], 1);
            atomicAdd(&s_hist[d.z >> 7], 1);
            atomicAdd(&s_hist[d.w >> 7], 1);
        }
    } else {
        for (int i = tid; i < cnt; i += 256) atomicAdd(&s_hist[dst[base + i] >> 7], 1);
    }
    __syncthreads();

    // phase 2: exclusive scan of 4-aligned run sizes -> padded run starts
    int per = (NB + 255) / 256;
    int st = tid * per;
    int lsum = 0;
    for (int j = 0; j < per; ++j)
        if (st + j < NB) lsum += (s_hist[st + j] + 3) & ~3;
    int excl = scan256_excl(lsum, s_scan);
    int padtot = s_scan[255];
    int run = excl;
    for (int j = 0; j < per; ++j)
        if (st + j < NB) { s_cur[st + j] = run; run += (s_hist[st + j] + 3) & ~3; }
    __syncthreads();

    // phase 3: re-read (L2-hot) and scatter into LDS, bucket-grouped
    if (cnt == CHUNK) {
        const int4* d4 = (const int4*)(dst + base);
        const int4* s4 = (const int4*)(src + base);
#pragma unroll
        for (int k = 0; k < CHUNK / 1024; ++k) {
            int4 d = d4[k * 256 + tid];
            int4 s = s4[k * 256 + tid];
            int dd[4] = {d.x, d.y, d.z, d.w};
            int ss[4] = {s.x, s.y, s.z, s.w};
#pragma unroll
            for (int j = 0; j < 4; ++j) {
                int pos = atomicAdd(&s_cur[dd[j] >> 7], 1);
                s_pk[pos] = ((unsigned)(dd[j] & 127) << 17) | (unsigned)ss[j];
            }
        }
    } else {
        for (int i = tid; i < cnt; i += 256) {
            int d = dst[base + i], s = src[base + i];
            int pos = atomicAdd(&s_cur[d >> 7], 1);
            s_pk[pos] = ((unsigned)(d & 127) << 17) | (unsigned)s;
        }
    }
    __syncthreads();

    // phase 4: block-major write + tables + bucket totals
    for (int i = tid; i < padtot; i += 256) packed[(size_t)blk * PSTR + i] = s_pk[i];
    for (int i = tid; i < NB; i += 256) {
        int h = s_hist[i];
        counts_bm[blk * NB + i] = h;
        lstart_bm[blk * NB + i] = s_cur[i] - h;
        if (h) atomicAdd(&btot[i], h);
    }
}

// ---- bucket_sort: self-computed region start, uint4 run gather -----------
__global__ __launch_bounds__(256)
void bucket_sort_kernel(const unsigned* __restrict__ packed,
                        const int* __restrict__ counts_bm,
                        const int* __restrict__ lstart_bm,
                        const int* __restrict__ btot,
                        int* __restrict__ csr_src, int* __restrict__ deg,
                        int* __restrict__ rowstart, int N, int NB, int NBLK) {
    __shared__ int s_cnt[MAXBLK], s_lst[MAXBLK], s_off[MAXBLK];
    __shared__ unsigned s_p[MAXB];
    __shared__ int s_out[MAXB];
    __shared__ int h[BW], hs[BW], curb[BW];
    __shared__ int s_scan[256];
    __shared__ int s_tot, s_ptot;
    int b = blockIdx.x, tid = threadIdx.x;

    // region start: prefix over buckets i<b of (align4(btot[i]) + 512)
    int partial = 0;
    for (int i = tid; i < b; i += 256) partial += ((btot[i] + 3) & ~3) + 512;
    scan256_excl(partial, s_scan);
    int beg = s_scan[255];

    for (int i = tid; i < NBLK; i += 256) {
        s_cnt[i] = counts_bm[i * NB + b];
        s_lst[i] = lstart_bm[i * NB + b];
    }
    __syncthreads();

    int per = (NBLK + 255) / 256;
    int st = tid * per;
    int lsum = 0;
    for (int j = 0; j < per; ++j)
        if (st + j < NBLK) lsum += s_cnt[st + j];
    int excl = scan256_excl(lsum, s_scan);
    if (tid == 255) s_tot = s_scan[255];
    int run = excl;
    for (int j = 0; j < per; ++j)
        if (st + j < NBLK) { s_off[st + j] = run; run += s_cnt[st + j]; }
    __syncthreads();
    int cnt = s_tot; if (cnt > MAXB) cnt = MAXB;

    // gather this bucket's runs with uint4 loads (runs 4-aligned)
    for (int blk = tid; blk < NBLK; blk += 256) {
        int c = s_cnt[blk], o = s_off[blk];
        const uint4* p = (const uint4*)(packed + (size_t)blk * PSTR + s_lst[blk]);
        for (int j = 0; j < c; j += 4) {
            uint4 v = p[j >> 2];
            int r = c - j;
            s_p[o + j] = v.x;
            if (r > 1) s_p[o + j + 1] = v.y;
            if (r > 2) s_p[o + j + 2] = v.z;
            if (r > 3) s_p[o + j + 3] = v.w;
        }
    }
    if (tid < BW) h[tid] = 0;
    __syncthreads();

    for (int i = tid; i < cnt; i += 256) atomicAdd(&h[s_p[i] >> 17], 1);
    __syncthreads();
    if (tid == 0) {
        int acc = 0;
        for (int i = 0; i < BW; ++i) { hs[i] = acc; acc += (h[i] + 3) & ~3; }
        s_ptot = acc;
    }
    __syncthreads();
    if (tid < BW) {
        curb[tid] = hs[tid];
        int node = b * BW + tid;
        if (node < N) { deg[node] = h[tid]; rowstart[node] = beg + hs[tid]; }
    }
    __syncthreads();
    for (int i = tid; i < cnt; i += 256) {
        unsigned p = s_p[i];
        int pos = atomicAdd(&curb[p >> 17], 1);
        s_out[pos] = (int)(p & 0x1FFFF);
    }
    __syncthreads();
    int ptot = s_ptot; if (ptot > MAXB) ptot = MAXB;
    for (int i = tid; i < ptot; i += 256) csr_src[beg + i] = s_out[i];
}

// ---- layer 1: h1 = sigmoid(mean(t1) + z1), 4 lanes per node --------------
__global__ __launch_bounds__(256)
void agg1_kernel(const _Float16* __restrict__ t1, const _Float16* __restrict__ z1,
                 const int* __restrict__ rowstart, const int* __restrict__ deg,
                 const int* __restrict__ csr, _Float16* __restrict__ h1, int n) {
    int idx = blockIdx.x * 256 + threadIdx.x;
    int node = idx >> 2, q = idx & 3;
    if (node >= n) return;
    int rs = rowstart[node], d = deg[node];
    float s[8];
    gather_quarter8((const half8*)t1, csr, rs, d, q, s);
    quad_reduce8(s);
    if (q == 0) {
        float inv = 1.0f / (float)(d > 0 ? d : 1);
        half8 z = ((const half8*)z1)[node];
        half8 o;
#pragma unroll
        for (int c = 0; c < 8; ++c) o[c] = (_Float16)sigmoidf_(s[c] * inv + (float)z[c]);
        ((half8*)h1)[node] = o;
    }
}

// ---- layer 2 + layer-3 transform, 4 lanes per node -----------------------
__global__ __launch_bounds__(256)
void gcn2_fused_kernel(const _Float16* __restrict__ h1,
                       const int* __restrict__ rowstart, const int* __restrict__ deg,
                       const int* __restrict__ csr,
                       const float* __restrict__ W2r, const float* __restrict__ b2,
                       const float* __restrict__ W2o,
                       const float* __restrict__ W3r, const float* __restrict__ b3,
                       const float* __restrict__ W3o,
                       _Float16* __restrict__ t3, _Float16* __restrict__ z3, int n) {
    __shared__ float sW2r[128], sW2o[128], sW3r[128], sW3o[128], sb2[16], sb3[8];
    int tid = threadIdx.x;
    if (tid < 128) {
        sW2r[tid] = W2r[tid]; sW2o[tid] = W2o[tid];
        sW3r[tid] = W3r[tid]; sW3o[tid] = W3o[tid];
    }
    if (tid < 16) sb2[tid] = b2[tid];
    if (tid < 8) sb3[tid] = b3[tid];
    __syncthreads();
    int idx = blockIdx.x * 256 + tid;
    int node = idx >> 2, q = idx & 3;
    if (node >= n) return;
    int rs = rowstart[node], d = deg[node];

    float m[8];
    gather_quarter8((const half8*)h1, csr, rs, d, q, m);
    quad_reduce8(m);
    if (q == 0) {
        float inv = 1.0f / (float)(d > 0 ? d : 1);
        half8 sf = ((const half8*)h1)[node];
        float x8[8];
#pragma unroll
        for (int c = 0; c < 8; ++c) { m[c] *= inv; x8[c] = (float)sf[c]; }

        float v16[16];
#pragma unroll
        for (int j = 0; j < 16; ++j) {
            float a = sb2[j];
#pragma unroll
            for (int f = 0; f < 8; ++f)
                a += m[f] * sW2r[f * 16 + j] + x8[f] * sW2o[f * 16 + j];
            v16[j] = sigmoidf_(a);
        }
        float ta[8], za[8];
#pragma unroll
        for (int j = 0; j < 8; ++j) { ta[j] = 0.0f; za[j] = sb3[j]; }
#pragma unroll
        for (int f = 0; f < 16; ++f) {
            float hv = v16[f];
#pragma unroll
            for (int j = 0; j < 8; ++j) {
                ta[j] += hv * sW3r[f * 8 + j];
                za[j] += hv * sW3o[f * 8 + j];
            }
        }
        half8 th, zh;
#pragma unroll
        for (int j = 0; j < 8; ++j) { th[j] = (_Float16)ta[j]; zh[j] = (_Float16)za[j]; }
        ((half8*)t3)[node] = th;
        ((half8*)z3)[node] = zh;
    }
}

// ---- layer 3 + full MLP head, 4 lanes per node ---------------------------
__global__ __launch_bounds__(256)
void agg3_mlp_kernel(const _Float16* __restrict__ t3, const _Float16* __restrict__ z3,
                     const int* __restrict__ rowstart, const int* __restrict__ deg,
                     const int* __restrict__ csr,
                     const float* __restrict__ fc1W, const float* __restrict__ fc1b,
                     const float* __restrict__ fc2W, const float* __restrict__ fc2b,
                     float* __restrict__ out, int n) {
    __shared__ float sW1[256], sb1[32], sW2[32];
    __shared__ float sb2_;
    int tid = threadIdx.x;
    if (tid < 256) sW1[tid] = fc1W[tid];
    if (tid < 32) { sb1[tid] = fc1b[tid]; sW2[tid] = fc2W[tid]; }
    if (tid == 0) sb2_ = fc2b[0];
    __syncthreads();
    int idx = blockIdx.x * 256 + tid;
    int node = idx >> 2, q = idx & 3;
    if (node >= n) return;
    int rs = rowstart[node], d = deg[node];

    float s[8];
    gather_quarter8((const half8*)t3, csr, rs, d, q, s);
    quad_reduce8(s);
    if (q == 0) {
        float inv = 1.0f / (float)(d > 0 ? d : 1);
        half8 z = ((const half8*)z3)[node];
        float h[8];
#pragma unroll
        for (int c = 0; c < 8; ++c) h[c] = sigmoidf_(s[c] * inv + (float)z[c]);
        float acc = sb2_;
#pragma unroll
        for (int j = 0; j < 32; ++j) {
            float a = sb1[j];
#pragma unroll
            for (int f = 0; f < 8; ++f) a += h[f] * sW1[f * 32 + j];
            acc += sW2[j] * sigmoidf_(a);
        }
        out[node] = acc;
    }
}

extern "C" void kernel_launch(void* const* d_in, const int* in_sizes, int n_in,
                              void* d_out, int out_size, void* d_ws, size_t ws_size,
                              hipStream_t stream) {
    const float* x      = (const float*)d_in[0];
    const int*   ei     = (const int*)d_in[1];
    const float* Wrel1  = (const float*)d_in[2];
    const float* b1     = (const float*)d_in[3];
    const float* Wroot1 = (const float*)d_in[4];
    const float* Wrel2  = (const float*)d_in[5];
    const float* b2     = (const float*)d_in[6];
    const float* Wroot2 = (const float*)d_in[7];
    const float* Wrel3  = (const float*)d_in[8];
    const float* b3     = (const float*)d_in[9];
    const float* Wroot3 = (const float*)d_in[10];
    const float* fc1W   = (const float*)d_in[11];
    const float* fc1b   = (const float*)d_in[12];
    const float* fc2W   = (const float*)d_in[13];
    const float* fc2b   = (const float*)d_in[14];
    float* out = (float*)d_out;

    const int N = in_sizes[0] / 16;
    const int E = in_sizes[1] / 2;
    const int* e_src = ei;
    const int* e_dst = ei + E;

    const int NB   = (N + BW - 1) / BW;           // 782
    const int NBLK = (E + CHUNK - 1) / CHUNK;     // 391
    const int nbN  = (N + 255) / 256;             // 391
    const int nb4  = (4 * N + 255) / 256;         // 1563

    char* ws = (char*)d_ws;
    size_t off = 0;
    auto alloc = [&](size_t bytes) { char* p = ws + off; off += (bytes + 15) & ~size_t(15); return p; };
    unsigned* packed   = (unsigned*)alloc((size_t)NBLK * PSTR * 4);
    int* counts_bm     = (int*)alloc((size_t)NBLK * NB * 4);
    int* lstart_bm     = (int*)alloc((size_t)NBLK * NB * 4);
    int* btot          = (int*)alloc((size_t)NB * 4);
    int* csr_src       = (int*)alloc(((size_t)E + (size_t)NB * 516) * 4);
    int* deg           = (int*)alloc((size_t)N * 4);
    int* rowstart      = (int*)alloc((size_t)N * 4);
    _Float16* t1       = (_Float16*)alloc((size_t)N * 8 * 2);
    _Float16* z1       = (_Float16*)alloc((size_t)N * 8 * 2);
    _Float16* h1       = (_Float16*)alloc((size_t)N * 8 * 2);
    _Float16* t3       = (_Float16*)alloc((size_t)N * 8 * 2);
    _Float16* z3       = (_Float16*)alloc((size_t)N * 8 * 2);

    hipMemsetAsync(btot, 0, (size_t)NB * 4, stream);

    const int gbuild = (NBLK > nbN) ? NBLK : nbN;
    bin_sort_kernel<<<gbuild, 256, 0, stream>>>(
        x, Wrel1, b1, Wroot1, t1, z1, e_src, e_dst,
        packed, counts_bm, lstart_bm, btot, E, N, NB, NBLK);
    bucket_sort_kernel<<<NB, 256, 0, stream>>>(packed, counts_bm, lstart_bm, btot,
                                               csr_src, deg, rowstart, N, NB, NBLK);
    agg1_kernel<<<nb4, 256, 0, stream>>>(t1, z1, rowstart, deg, csr_src, h1, N);
    gcn2_fused_kernel<<<nb4, 256, 0, stream>>>(h1, rowstart, deg, csr_src,
                                               Wrel2, b2, Wroot2, Wrel3, b3, Wroot3, t3, z3, N);
    agg3_mlp_kernel<<<nb4, 256, 0, stream>>>(t3, z3, rowstart, deg, csr_src,
                                             fc1W, fc1b, fc2W, fc2b, out, N);
}